// Round 1
// baseline (535.013 us; speedup 1.0000x reference)
//
#include <hip/hip_runtime.h>

typedef unsigned long long u64;
typedef unsigned int u32;

static constexpr int NF = 17;      // features per point
static constexpr int BCOL = 9;     // beta column
static constexpr int CCOL = 14;    // first ccoord column (17-3)
static constexpr int CONDCAP = 256;

#define T_B_F ((float)0.2)         // matches numpy float32(0.2)
#define R2_F  ((float)(0.7*0.7))   // matches numpy float32(0.48999999999999994)

__device__ __forceinline__ u64 kmax(u64 a, u64 b){ return a > b ? a : b; }

__device__ __forceinline__ u64 shfl_down_u64(u64 v, int off){
    u32 lo = (u32)v, hi = (u32)(v >> 32);
    lo = __shfl_down(lo, off, 64);
    hi = __shfl_down(hi, off, 64);
    return ((u64)hi << 32) | lo;
}

__device__ __forceinline__ u64 waveReduceMax(u64 k){
    #pragma unroll
    for (int off = 32; off > 0; off >>= 1){
        u64 o = shfl_down_u64(k, off);
        if (o > k) k = o;
    }
    return k;
}

// distance with NO fp contraction — must match numpy (mul,mul,mul,add,add)
__device__ __forceinline__ float dist2(float cx, float cy, float cz,
                                       float rx, float ry, float rz){
    #pragma clang fp contract(off)
    float dx = cx - rx, dy = cy - ry, dz = cz - rz;
    float sx = dx * dx, sy = dy * dy, sz = dz * dz;
    return (sx + sy) + sz;
}

__device__ __forceinline__ u64 makeKey(float beta, u32 idx){
    return ((u64)__float_as_uint(beta) << 32) | (u64)(0xFFFFFFFFu - idx);
}

// ---------------- kernel 0: zero counters ----------------
__global__ void k_init(u32* ws){
    int t = threadIdx.x;
    if (t < 1024) ws[t] = 0;   // zero first 4 KB: argmax[3][E], cnt[3][E], ncond[E]
}

// ---------------- kernel 1: zero dout + filter beta>=T_B + per-event argmax ----
__global__ __launch_bounds__(256) void k_filter(
    const float* __restrict__ x, float* __restrict__ out,
    u64* __restrict__ argmax0, int* __restrict__ cnt0,
    float4* __restrict__ cA, int* __restrict__ iA,
    int P, int chunksPerEvent, int rowsPerBlock)
{
    int e = blockIdx.x / chunksPerEvent;
    int chunk = blockIdx.x % chunksPerEvent;
    int rowStart = chunk * rowsPerBlock;                 // within event
    size_t gRow0 = (size_t)e * P + rowStart;

    // zero this block's slice of dout (rowsPerBlock*17 floats, 16B aligned)
    {
        float4* ov = (float4*)out + gRow0 * NF / 4;
        int n4 = rowsPerBlock * NF / 4;
        float4 z = make_float4(0.f, 0.f, 0.f, 0.f);
        for (int i = threadIdx.x; i < n4; i += 256) ov[i] = z;
    }

    int lid = threadIdx.x & 63, wid = threadIdx.x >> 6;
    u64 localKey = 0;
    int iters = rowsPerBlock / 256;
    for (int k = 0; k < iters; k++){
        int p = rowStart + k * 256 + threadIdx.x;
        size_t base = ((size_t)e * P + p) * NF;
        float beta = x[base + BCOL];
        float cx = x[base + CCOL], cy = x[base + CCOL + 1], cz = x[base + CCOL + 2];
        bool keep = (beta >= T_B_F);
        u64 bal = __ballot(keep);
        int cw = __popcll(bal);
        int b_ = 0;
        if (lid == 0) b_ = cw ? atomicAdd(&cnt0[e], cw) : 0;
        b_ = __shfl(b_, 0, 64);
        if (keep){
            int pos = b_ + __popcll(bal & ((1ull << lid) - 1));
            cA[(size_t)e * P + pos] = make_float4(cx, cy, cz, beta);
            iA[(size_t)e * P + pos] = p;
            localKey = kmax(localKey, makeKey(beta, (u32)p));
        }
    }
    __shared__ u64 sred[4];
    u64 kw = waveReduceMax(localKey);
    if (lid == 0) sred[wid] = kw;
    __syncthreads();
    if (threadIdx.x == 0){
        u64 m = sred[0];
        for (int i = 1; i < 4; i++) m = kmax(m, sred[i]);
        if (m) atomicMax(&argmax0[e], m);
    }
}

// ---------------- kernel 2: one full-grid NMS round (remove ball, compact, next argmax)
__global__ __launch_bounds__(256) void k_pass(
    const float* __restrict__ x,
    const float4* __restrict__ cIn, const int* __restrict__ iIn,
    float4* __restrict__ cOut, int* __restrict__ iOut,
    const u64* __restrict__ argmaxIn, u64* __restrict__ argmaxOut,
    const int* __restrict__ cntIn, int* __restrict__ cntOut,
    int* __restrict__ ncond, int* __restrict__ condlist,
    int P, int blocksPerEvent)
{
    int e = blockIdx.x / blocksPerEvent;
    int c = blockIdx.x % blocksPerEvent;
    u64 key = argmaxIn[e];
    float betaRef = __uint_as_float((u32)(key >> 32));
    if (!(betaRef >= T_B_F)) return;   // event finished (uniform across its blocks)
    u32 refIdx = 0xFFFFFFFFu - (u32)(key & 0xFFFFFFFFu);
    if (c == 0 && threadIdx.x == 0){
        int s = atomicAdd(&ncond[e], 1);
        if (s < CONDCAP) condlist[e * CONDCAP + s] = (int)refIdx;
    }
    size_t rbase = ((size_t)e * P + refIdx) * NF;
    float rx = x[rbase + CCOL], ry = x[rbase + CCOL + 1], rz = x[rbase + CCOL + 2];

    int n = cntIn[e];
    int lid = threadIdx.x & 63, wid = threadIdx.x >> 6;
    u64 localKey = 0;
    int stride = blocksPerEvent * 256;
    for (int i = c * 256 + threadIdx.x; i < n; i += stride){
        float4 cc = cIn[(size_t)e * P + i];
        int idx = iIn[(size_t)e * P + i];
        float d2 = dist2(cc.x, cc.y, cc.z, rx, ry, rz);
        bool keep = !(d2 <= R2_F);
        u64 bal = __ballot(keep);
        int cw = __popcll(bal);
        int b_ = 0;
        if (lid == 0) b_ = cw ? atomicAdd(&cntOut[e], cw) : 0;
        b_ = __shfl(b_, 0, 64);
        if (keep){
            int pos = b_ + __popcll(bal & ((1ull << lid) - 1));
            cOut[(size_t)e * P + pos] = cc;
            iOut[(size_t)e * P + pos] = idx;
            localKey = kmax(localKey, makeKey(cc.w, (u32)idx));
        }
    }
    __shared__ u64 sred[4];
    u64 kw = waveReduceMax(localKey);
    if (lid == 0) sred[wid] = kw;
    __syncthreads();
    if (threadIdx.x == 0){
        u64 m = sred[0];
        for (int i = 1; i < 4; i++) m = kmax(m, sred[i]);
        if (m) atomicMax(&argmaxOut[e], m);
    }
}

// ---------------- kernel 3: per-event finish (one block/event, device-side loop)
__global__ __launch_bounds__(1024) void k_finish(
    const float* __restrict__ x,
    float4* cA, int* iA, float4* cB, int* iB,
    const u64* __restrict__ argmax2, const int* __restrict__ cnt2,
    int* __restrict__ ncond, int* __restrict__ condlist, int P)
{
    int e = blockIdx.x;
    __shared__ u64 sred[16];
    __shared__ int scnt;
    __shared__ u64 skey;
    __shared__ float srefc[3];

    int n = cnt2[e];
    u64 key = argmax2[e];
    float4* cIn = cA + (size_t)e * P; int* iIn = iA + (size_t)e * P;
    float4* cOut = cB + (size_t)e * P; int* iOut = iB + (size_t)e * P;
    int tid = threadIdx.x, lid = tid & 63, wid = tid >> 6;

    while (true){
        float betaRef = __uint_as_float((u32)(key >> 32));
        if (!(betaRef >= T_B_F)) break;          // uniform decision
        u32 refIdx = 0xFFFFFFFFu - (u32)(key & 0xFFFFFFFFu);
        if (tid == 0){
            int s = atomicAdd(&ncond[e], 1);
            if (s < CONDCAP) condlist[e * CONDCAP + s] = (int)refIdx;
            size_t rbase = ((size_t)e * P + refIdx) * NF;
            srefc[0] = x[rbase + CCOL];
            srefc[1] = x[rbase + CCOL + 1];
            srefc[2] = x[rbase + CCOL + 2];
            scnt = 0;
        }
        __syncthreads();                          // (A)
        float rx = srefc[0], ry = srefc[1], rz = srefc[2];
        u64 localKey = 0;
        for (int i = tid; i < n; i += 1024){
            float4 cc = cIn[i]; int idx = iIn[i];
            float d2 = dist2(cc.x, cc.y, cc.z, rx, ry, rz);
            bool keep = !(d2 <= R2_F);
            u64 bal = __ballot(keep);
            int cw = __popcll(bal);
            int b_ = 0;
            if (lid == 0) b_ = cw ? atomicAdd(&scnt, cw) : 0;
            b_ = __shfl(b_, 0, 64);
            if (keep){
                int pos = b_ + __popcll(bal & ((1ull << lid) - 1));
                cOut[pos] = cc; iOut[pos] = idx;
                localKey = kmax(localKey, makeKey(cc.w, (u32)idx));
            }
        }
        u64 kw = waveReduceMax(localKey);
        if (lid == 0) sred[wid] = kw;
        __syncthreads();                          // (B)
        if (tid == 0){
            u64 m = 0;
            for (int i = 0; i < 16; i++) m = kmax(m, sred[i]);
            skey = m;
        }
        __syncthreads();                          // (C)
        key = skey;
        n = scnt;
        { float4* t = cIn; cIn = cOut; cOut = t; }
        { int* t = iIn; iIn = iOut; iOut = t; }
        __syncthreads();                          // (D) protect scnt/srefc reuse
    }
}

// ---------------- kernel 4: row_splits (as float32) + scatter condensate rows
__global__ void k_out(const float* __restrict__ x, float* __restrict__ out,
                      const int* __restrict__ ncond, const int* __restrict__ condlist,
                      int P, int E)
{
    int e = blockIdx.x;
    if (e == 0 && threadIdx.x < E + 1){
        int s = 0;
        for (int i = 0; i < (int)threadIdx.x; i++) s += ncond[i];
        out[(size_t)E * P * NF + threadIdx.x] = (float)s;
    }
    int nc = ncond[e];
    if (nc > CONDCAP) nc = CONDCAP;
    int tot = nc * NF;
    for (int i = threadIdx.x; i < tot; i += blockDim.x){
        int j = i / NF, f = i - j * NF;
        int row = condlist[e * CONDCAP + j];
        size_t base = ((size_t)e * P + row) * NF;
        out[base + f] = x[base + f];
    }
}

extern "C" void kernel_launch(void* const* d_in, const int* in_sizes, int n_in,
                              void* d_out, int out_size, void* d_ws, size_t ws_size,
                              hipStream_t stream) {
    const float* x = (const float*)d_in[0];
    int N = in_sizes[0] / NF;
    int E = in_sizes[1] - 1;
    int P = N / E;
    float* out = (float*)d_out;
    char* ws = (char*)d_ws;

    // ws layout
    u64* argmax = (u64*)ws;                         // [3][E]  (E<=16 -> <=384B)
    int* cnt    = (int*)(ws + 512);                 // [3][E]
    int* ncond  = (int*)(ws + 768);                 // [E]
    int* condlist = (int*)(ws + 1024);              // [E][CONDCAP] ints
    size_t listOff = 32768;
    size_t listElems = (size_t)E * P;
    float4* cA = (float4*)(ws + listOff);
    float4* cB = (float4*)(ws + listOff + listElems * 16);
    int* iA = (int*)(ws + listOff + listElems * 32);
    int* iB = (int*)(ws + listOff + listElems * 36);

    k_init<<<1, 1024, 0, stream>>>((u32*)ws);

    int chunksPerEvent = 128;
    int rowsPerBlock = P / chunksPerEvent;          // 512
    k_filter<<<E * chunksPerEvent, 256, 0, stream>>>(
        x, out, argmax, cnt, cA, iA, P, chunksPerEvent, rowsPerBlock);

    int bpe = 32;
    k_pass<<<E * bpe, 256, 0, stream>>>(
        x, cA, iA, cB, iB, argmax, argmax + E, cnt, cnt + E,
        ncond, condlist, P, bpe);
    k_pass<<<E * bpe, 256, 0, stream>>>(
        x, cB, iB, cA, iA, argmax + E, argmax + 2 * E, cnt + E, cnt + 2 * E,
        ncond, condlist, P, bpe);

    k_finish<<<E, 1024, 0, stream>>>(
        x, cA, iA, cB, iB, argmax + 2 * E, cnt + 2 * E, ncond, condlist, P);

    k_out<<<E, 256, 0, stream>>>(x, out, ncond, condlist, P, E);
}

// Round 2
// 193.263 us; speedup vs baseline: 2.7683x; 2.7683x over previous
//
#include <hip/hip_runtime.h>

typedef unsigned long long u64;
typedef unsigned int u32;

static constexpr int NF = 17;      // features per point
static constexpr int BCOL = 9;     // beta column
static constexpr int CCOL = 14;    // first ccoord column (17-3)
static constexpr int CONDCAP = 256;
static constexpr int NPASS = 4;    // grid-wide NMS rounds before k_finish
static constexpr int RPB = 512;    // rows per block in k_filter
static constexpr int MAXIT = 8;    // max per-thread iters in k_pass (8*32*256 = 65536 = P)

#define T_B_F ((float)0.2)         // matches numpy float32(0.2)
#define R2_F  ((float)(0.7*0.7))   // matches numpy float32(0.49000000953674316 via double)

__device__ __forceinline__ u64 kmax(u64 a, u64 b){ return a > b ? a : b; }

__device__ __forceinline__ u64 shfl_down_u64(u64 v, int off){
    u32 lo = (u32)v, hi = (u32)(v >> 32);
    lo = __shfl_down(lo, off, 64);
    hi = __shfl_down(hi, off, 64);
    return ((u64)hi << 32) | lo;
}

__device__ __forceinline__ u64 waveReduceMax(u64 k){
    #pragma unroll
    for (int off = 32; off > 0; off >>= 1){
        u64 o = shfl_down_u64(k, off);
        if (o > k) k = o;
    }
    return k;
}

// distance with NO fp contraction — must match numpy (mul,mul,mul,add,add)
__device__ __forceinline__ float dist2(float cx, float cy, float cz,
                                       float rx, float ry, float rz){
    #pragma clang fp contract(off)
    float dx = cx - rx, dy = cy - ry, dz = cz - rz;
    float sx = dx * dx, sy = dy * dy, sz = dz * dz;
    return (sx + sy) + sz;
}

__device__ __forceinline__ u64 makeKey(float beta, u32 idx){
    return ((u64)__float_as_uint(beta) << 32) | (u64)(0xFFFFFFFFu - idx);
}

// ---------------- kernel 0: zero control block (4 KB) ----------------
__global__ void k_init(u32* ws){
    int t = threadIdx.x;
    if (t < 1024) ws[t] = 0;   // argmax[NPASS+1][E], cnt[NPASS+1][E], ncond[E]
}

// ---------------- kernel 1: zero dout + filter beta>=T_B + per-event argmax ----
// Coalesced: stage 512-row tile via float4 through LDS; fused zero-fill of out.
// ONE atomicAdd per block (order in the compacted list is irrelevant).
__global__ __launch_bounds__(256) void k_filter(
    const float4* __restrict__ x4, float4* __restrict__ out4,
    u64* __restrict__ argmax0, int* __restrict__ cnt0,
    float4* __restrict__ cA, int* __restrict__ iA,
    int P, int chunksPerEvent)
{
    __shared__ float lds[RPB * NF];           // 34816 B
    __shared__ int swc[4], swb[4], sbase;
    __shared__ u64 sred[4];

    int e = blockIdx.x / chunksPerEvent;
    int chunk = blockIdx.x % chunksPerEvent;
    int rowStart = chunk * RPB;
    size_t tile4 = (size_t)blockIdx.x * (RPB * NF / 4);   // 2176 float4 per tile

    float4* lds4 = (float4*)lds;
    const int N4 = RPB * NF / 4;
    float4 z = make_float4(0.f, 0.f, 0.f, 0.f);
    for (int i = threadIdx.x; i < N4; i += 256){
        lds4[i] = x4[tile4 + i];
        out4[tile4 + i] = z;                   // fused zero of dout
    }
    __syncthreads();

    int tid = threadIdx.x, lid = tid & 63, wid = tid >> 6;
    int r0 = tid, r1 = tid + 256;
    float be0 = lds[r0*NF+BCOL], cx0 = lds[r0*NF+CCOL], cy0 = lds[r0*NF+CCOL+1], cz0 = lds[r0*NF+CCOL+2];
    float be1 = lds[r1*NF+BCOL], cx1 = lds[r1*NF+CCOL], cy1 = lds[r1*NF+CCOL+1], cz1 = lds[r1*NF+CCOL+2];
    bool k0 = (be0 >= T_B_F), k1 = (be1 >= T_B_F);
    u64 bal0 = __ballot(k0), bal1 = __ballot(k1);
    int wcnt = __popcll(bal0) + __popcll(bal1);

    u64 lk = 0;
    if (k0) lk = makeKey(be0, (u32)(rowStart + r0));
    if (k1) lk = kmax(lk, makeKey(be1, (u32)(rowStart + r1)));
    u64 kw = waveReduceMax(lk);
    if (lid == 0){ swc[wid] = wcnt; sred[wid] = kw; }
    __syncthreads();
    if (tid == 0){
        int tot = 0;
        for (int w = 0; w < 4; w++){ swb[w] = tot; tot += swc[w]; }
        sbase = tot ? atomicAdd(&cnt0[e], tot) : 0;      // 1 returning atomic / block
        u64 m = sred[0];
        for (int i = 1; i < 4; i++) m = kmax(m, sred[i]);
        if (m) atomicMax(&argmax0[e], m);                // fire-and-forget
    }
    __syncthreads();
    int base = sbase + swb[wid];
    u64 lm = (1ull << lid) - 1;
    size_t eoff = (size_t)e * P;
    if (k0){
        int pos = base + __popcll(bal0 & lm);
        cA[eoff + pos] = make_float4(cx0, cy0, cz0, be0);
        iA[eoff + pos] = rowStart + r0;
    }
    if (k1){
        int pos = base + __popcll(bal0) + __popcll(bal1 & lm);
        cA[eoff + pos] = make_float4(cx1, cy1, cz1, be1);
        iA[eoff + pos] = rowStart + r1;
    }
}

// ---------------- kernel 2: one grid-wide NMS round; ONE atomic per block ------
__global__ __launch_bounds__(256) void k_pass(
    const float* __restrict__ x,
    const float4* __restrict__ cIn, const int* __restrict__ iIn,
    float4* __restrict__ cOut, int* __restrict__ iOut,
    const u64* __restrict__ argmaxIn, u64* __restrict__ argmaxOut,
    const int* __restrict__ cntIn, int* __restrict__ cntOut,
    int* __restrict__ ncond, int* __restrict__ condlist,
    int P, int blocksPerEvent)
{
    __shared__ int swc[4], swb[4], sbase;
    __shared__ u64 sred[4];

    int e = blockIdx.x / blocksPerEvent;
    int c = blockIdx.x % blocksPerEvent;
    u64 key = argmaxIn[e];
    float betaRef = __uint_as_float((u32)(key >> 32));
    if (!(betaRef >= T_B_F)) return;   // event finished (uniform across its blocks)
    u32 refIdx = 0xFFFFFFFFu - (u32)(key & 0xFFFFFFFFu);
    if (c == 0 && threadIdx.x == 0){
        int s = atomicAdd(&ncond[e], 1);
        if (s < CONDCAP) condlist[e * CONDCAP + s] = (int)refIdx;
    }
    size_t rbase = ((size_t)e * P + refIdx) * NF;
    float rx = x[rbase + CCOL], ry = x[rbase + CCOL + 1], rz = x[rbase + CCOL + 2];

    int n = cntIn[e];
    int tid = threadIdx.x, lid = tid & 63, wid = tid >> 6;
    size_t eoff = (size_t)e * P;
    int stride = blocksPerEvent * 256;

    float4 cc[MAXIT]; int ix[MAXIT]; bool kp[MAXIT]; u64 bal[MAXIT];
    int wcnt = 0;
    u64 lk = 0;
    #pragma unroll
    for (int k = 0; k < MAXIT; k++){
        int i = c * 256 + tid + k * stride;
        bool inb = i < n;
        int ii = inb ? i : 0;
        cc[k] = cIn[eoff + ii];
        ix[k] = iIn[eoff + ii];
        float d2 = dist2(cc[k].x, cc[k].y, cc[k].z, rx, ry, rz);
        kp[k] = inb && !(d2 <= R2_F);
        bal[k] = __ballot(kp[k]);
        wcnt += __popcll(bal[k]);
        if (kp[k]) lk = kmax(lk, makeKey(cc[k].w, (u32)ix[k]));
    }
    u64 kw = waveReduceMax(lk);
    if (lid == 0){ swc[wid] = wcnt; sred[wid] = kw; }
    __syncthreads();
    if (tid == 0){
        int tot = 0;
        for (int w = 0; w < 4; w++){ swb[w] = tot; tot += swc[w]; }
        sbase = tot ? atomicAdd(&cntOut[e], tot) : 0;
        u64 m = sred[0];
        for (int i = 1; i < 4; i++) m = kmax(m, sred[i]);
        if (m) atomicMax(&argmaxOut[e], m);
    }
    __syncthreads();
    int pos = sbase + swb[wid];
    u64 lm = (1ull << lid) - 1;
    #pragma unroll
    for (int k = 0; k < MAXIT; k++){
        if (kp[k]){
            int p_ = pos + __popcll(bal[k] & lm);
            cOut[eoff + p_] = cc[k];
            iOut[eoff + p_] = ix[k];
        }
        pos += __popcll(bal[k]);
    }
}

// ---------------- kernel 3: per-event finish (one block/event, device-side loop)
__global__ __launch_bounds__(1024) void k_finish(
    const float* __restrict__ x,
    float4* cA, int* iA, float4* cB, int* iB,
    const u64* __restrict__ argmax2, const int* __restrict__ cnt2,
    int* __restrict__ ncond, int* __restrict__ condlist, int P)
{
    int e = blockIdx.x;
    __shared__ u64 sred[16];
    __shared__ int scnt;
    __shared__ u64 skey;
    __shared__ float srefc[3];

    int n = cnt2[e];
    u64 key = argmax2[e];
    float4* cIn = cA + (size_t)e * P; int* iIn = iA + (size_t)e * P;
    float4* cOut = cB + (size_t)e * P; int* iOut = iB + (size_t)e * P;
    int tid = threadIdx.x, lid = tid & 63, wid = tid >> 6;

    while (true){
        float betaRef = __uint_as_float((u32)(key >> 32));
        if (!(betaRef >= T_B_F)) break;          // uniform decision
        u32 refIdx = 0xFFFFFFFFu - (u32)(key & 0xFFFFFFFFu);
        if (tid == 0){
            int s = atomicAdd(&ncond[e], 1);
            if (s < CONDCAP) condlist[e * CONDCAP + s] = (int)refIdx;
            size_t rbase = ((size_t)e * P + refIdx) * NF;
            srefc[0] = x[rbase + CCOL];
            srefc[1] = x[rbase + CCOL + 1];
            srefc[2] = x[rbase + CCOL + 2];
            scnt = 0;
        }
        __syncthreads();                          // (A)
        float rx = srefc[0], ry = srefc[1], rz = srefc[2];
        u64 localKey = 0;
        for (int i = tid; i < n; i += 1024){
            float4 cc = cIn[i]; int idx = iIn[i];
            float d2 = dist2(cc.x, cc.y, cc.z, rx, ry, rz);
            bool keep = !(d2 <= R2_F);
            u64 bal = __ballot(keep);
            int cw = __popcll(bal);
            int b_ = 0;
            if (lid == 0) b_ = cw ? atomicAdd(&scnt, cw) : 0;
            b_ = __shfl(b_, 0, 64);
            if (keep){
                int pos = b_ + __popcll(bal & ((1ull << lid) - 1));
                cOut[pos] = cc; iOut[pos] = idx;
                localKey = kmax(localKey, makeKey(cc.w, (u32)idx));
            }
        }
        u64 kw = waveReduceMax(localKey);
        if (lid == 0) sred[wid] = kw;
        __syncthreads();                          // (B)
        if (tid == 0){
            u64 m = 0;
            for (int i = 0; i < 16; i++) m = kmax(m, sred[i]);
            skey = m;
        }
        __syncthreads();                          // (C)
        key = skey;
        n = scnt;
        { float4* t = cIn; cIn = cOut; cOut = t; }
        { int* t = iIn; iIn = iOut; iOut = t; }
        __syncthreads();                          // (D) protect scnt/srefc reuse
    }
}

// ---------------- kernel 4: row_splits (as float32) + scatter condensate rows
__global__ void k_out(const float* __restrict__ x, float* __restrict__ out,
                      const int* __restrict__ ncond, const int* __restrict__ condlist,
                      int P, int E)
{
    int e = blockIdx.x;
    if (e == 0 && threadIdx.x < E + 1){
        int s = 0;
        for (int i = 0; i < (int)threadIdx.x; i++) s += ncond[i];
        out[(size_t)E * P * NF + threadIdx.x] = (float)s;
    }
    int nc = ncond[e];
    if (nc > CONDCAP) nc = CONDCAP;
    int tot = nc * NF;
    for (int i = threadIdx.x; i < tot; i += blockDim.x){
        int j = i / NF, f = i - j * NF;
        int row = condlist[e * CONDCAP + j];
        size_t base = ((size_t)e * P + row) * NF;
        out[base + f] = x[base + f];
    }
}

extern "C" void kernel_launch(void* const* d_in, const int* in_sizes, int n_in,
                              void* d_out, int out_size, void* d_ws, size_t ws_size,
                              hipStream_t stream) {
    const float* x = (const float*)d_in[0];
    int N = in_sizes[0] / NF;
    int E = in_sizes[1] - 1;
    int P = N / E;
    float* out = (float*)d_out;
    char* ws = (char*)d_ws;

    // ws layout (first 4 KB zeroed by k_init)
    u64* argmax = (u64*)ws;                         // [NPASS+1][E]
    int* cnt    = (int*)(ws + 1024);                // [NPASS+1][E]
    int* ncond  = (int*)(ws + 2048);                // [E]
    int* condlist = (int*)(ws + 4096);              // [E][CONDCAP]
    size_t listOff = 32768;
    size_t listElems = (size_t)E * P;
    float4* cA = (float4*)(ws + listOff);
    float4* cB = (float4*)(ws + listOff + listElems * 16);
    int* iA = (int*)(ws + listOff + listElems * 32);
    int* iB = (int*)(ws + listOff + listElems * 36);

    k_init<<<1, 1024, 0, stream>>>((u32*)ws);

    int chunksPerEvent = P / RPB;                   // 128
    k_filter<<<E * chunksPerEvent, 256, 0, stream>>>(
        (const float4*)x, (float4*)out, argmax, cnt, cA, iA, P, chunksPerEvent);

    int bpe = 32;                                   // 32*256*MAXIT = 65536 = P coverage
    float4* cs[2] = {cA, cB};
    int* is[2] = {iA, iB};
    for (int r = 0; r < NPASS; r++){
        k_pass<<<E * bpe, 256, 0, stream>>>(
            x, cs[r & 1], is[r & 1], cs[(r + 1) & 1], is[(r + 1) & 1],
            argmax + r * E, argmax + (r + 1) * E,
            cnt + r * E, cnt + (r + 1) * E,
            ncond, condlist, P, bpe);
    }

    // NPASS even -> current list is back in cA
    k_finish<<<E, 1024, 0, stream>>>(
        x, cA, iA, cB, iB, argmax + NPASS * E, cnt + NPASS * E, ncond, condlist, P);

    k_out<<<E, 256, 0, stream>>>(x, out, ncond, condlist, P, E);
}